// Round 7
// baseline (171.410 us; speedup 1.0000x reference)
//
#include <hip/hip_runtime.h>

#define BS      128
#define NF      4
#define NC      36
#define P_LO    1024
#define P_HI    16384
#define KNN     9
#define THREADS 256
#define TILE_P  512
#define TILE_F  (TILE_P * KNN)       // 4608 elems per tile (idx or weights)
#define NTILES  (P_HI / TILE_P)      // 32 (each tile = 4 hi rows)
#define SGRP    8                    // samples staged per group
#define YROWS   192                  // 6 lo rows staged (span needs 4; +2 margin)
#define LIST_OFF 64                  // ints: ws[0..35]=counts, ws[64+c*128+i]=ids

// ---- pre-pass: bucket samples by class (ws usage: 4.7K ints, R4-proven) ----
__global__ __launch_bounds__(128) void build_lists_kernel(
    const int* __restrict__ cls_ids, int* __restrict__ ws)
{
    __shared__ int cnt[NC];
    const int t = threadIdx.x;
    if (t < NC) cnt[t] = 0;
    __syncthreads();
    if (t < BS) {
        int c = cls_ids[t];
        int pos = atomicAdd(&cnt[c], 1);
        ws[LIST_OFF + c * BS + pos] = t;
    }
    __syncthreads();
    if (t < NC) ws[t] = cnt[t];
}

// ---- main: block = (cls, f, tile); sweep samples of cls in groups ----
__global__ __launch_bounds__(THREADS) void rect_up_kernel(
    const float* __restrict__ x,       // (BS, NF*P_LO)
    const int*   __restrict__ ws,      // counts + lists
    const int*   __restrict__ nbr,     // (P_HI, K)
    const float* __restrict__ wmap,    // (NC, NF, P_HI, K)
    const float* __restrict__ blo,     // (NC, NF, P_LO)
    const float* __restrict__ bhi,     // (NC, NF, P_HI)
    float*       __restrict__ out)     // (BS, NF, P_HI)
{
    __shared__ __align__(16) int   stage[TILE_F];       // 18432 B, reused
    __shared__ __align__(16) float bl_s[YROWS];         // 768 B
    __shared__ __align__(16) float ybuf[SGRP * YROWS];  // 6144 B

    const int tile = blockIdx.x % NTILES;
    const int cf   = blockIdx.x / NTILES;
    const int f    = cf % NF;
    const int cls  = cf / NF;

    const int n_b = ws[cls];
    if (n_b == 0) return;             // uniform exit before any barrier

    const int tid = threadIdx.x;
    int start = tile - 2;             // lo-row window [start, start+6)
    if (start < 0)  start = 0;
    if (start > 26) start = 26;
    const int rebase = start * 32;

    // ---- stage neighbor indices for this tile (coalesced int4) ----
    const int4* isrc = (const int4*)(nbr + (size_t)tile * TILE_P * KNN);
    for (int i = tid; i < TILE_F / 4; i += THREADS)
        ((int4*)stage)[i] = isrc[i];
    __syncthreads();

    // readback local offsets: flat 18 = [p0 k0..k8, p1 k0..k8]
    int nb[18];
    {
        const int2* ir = (const int2*)stage + (size_t)tid * 9;
        #pragma unroll
        for (int j = 0; j < 9; ++j) {
            int2 c = ir[j];
            nb[2 * j]     = c.x - rebase;
            nb[2 * j + 1] = c.y - rebase;
        }
    }
    __syncthreads();                  // stage now free -> weights

    // ---- stage weight tile (coalesced float4) + bias_low slice ----
    const float4* wsrc = (const float4*)(wmap +
        ((size_t)(cls * NF + f) * P_HI + (size_t)tile * TILE_P) * KNN);
    float* w_st = (float*)stage;
    for (int i = tid; i < TILE_F / 4; i += THREADS)
        ((float4*)w_st)[i] = wsrc[i];
    if (tid < YROWS / 4)
        ((float4*)bl_s)[tid] =
            ((const float4*)(blo + (cls * NF + f) * P_LO + rebase))[tid];
    __syncthreads();

    // readback weights, same flat layout as nb
    float wl[18];
    {
        const float2* wr = (const float2*)w_st + (size_t)tid * 9;
        #pragma unroll
        for (int j = 0; j < 9; ++j) {
            float2 a = wr[j];
            wl[2 * j]     = a.x;
            wl[2 * j + 1] = a.y;
        }
    }

    const int    p0   = tile * TILE_P + 2 * tid;
    const float2 bh   = *(const float2*)(bhi + (size_t)(cls * NF + f) * P_HI + p0);
    const int*   list = ws + LIST_OFF + cls * BS;

    for (int g = 0; g < n_b; g += SGRP) {
        const int cnt = min(SGRP, n_b - g);
        __syncthreads();              // ybuf free (prev group done)
        {   // stage cnt sample slices: 32 threads per sample, 48 float4 each
            const int si = tid >> 5;
            const int el = tid & 31;
            if (si < cnt) {
                const int    b  = list[g + si];
                const float4* xs = (const float4*)(x + (b * NF + f) * P_LO + rebase);
                #pragma unroll
                for (int i = el; i < YROWS / 4; i += 32) {
                    float4 xv = xs[i];
                    float4 bv = ((const float4*)bl_s)[i];
                    float4 r;
                    r.x = xv.x - bv.x; r.y = xv.y - bv.y;
                    r.z = xv.z - bv.z; r.w = xv.w - bv.w;
                    ((float4*)ybuf)[si * (YROWS / 4) + i] = r;
                }
            }
        }
        __syncthreads();
        for (int s = 0; s < cnt; ++s) {
            const float* y = ybuf + s * YROWS;
            const int    b = list[g + s];
            float a0 = 0.f, a1 = 0.f;
            #pragma unroll
            for (int j = 0; j < 9; ++j) a0 = fmaf(wl[j],     y[nb[j]],     a0);
            #pragma unroll
            for (int j = 0; j < 9; ++j) a1 = fmaf(wl[9 + j], y[nb[9 + j]], a1);
            float2 o;
            o.x = a0 + bh.x;
            o.y = a1 + bh.y;
            *(float2*)(out + (size_t)(b * NF + f) * P_HI + p0) = o;
        }
    }
}

extern "C" void kernel_launch(void* const* d_in, const int* in_sizes, int n_in,
                              void* d_out, int out_size, void* d_ws, size_t ws_size,
                              hipStream_t stream) {
    const float* x    = (const float*)d_in[0];
    const int*   cls  = (const int*)d_in[1];
    const int*   nbr  = (const int*)d_in[2];
    const float* wmap = (const float*)d_in[3];
    const float* blo  = (const float*)d_in[4];
    const float* bhi  = (const float*)d_in[5];
    float*       out  = (float*)d_out;
    int*         wsl  = (int*)d_ws;   // (64 + 36*128)*4 = 18.7 KB (R4-proven)

    build_lists_kernel<<<1, 128, 0, stream>>>(cls, wsl);
    rect_up_kernel<<<NC * NF * NTILES, THREADS, 0, stream>>>(
        x, wsl, nbr, wmap, blo, bhi, out);
}